// Round 1
// 617.284 us; speedup vs baseline: 1.0470x; 1.0470x over previous
//
#include <hip/hip_runtime.h>
#include <hip/hip_fp16.h>

typedef unsigned short u16;
typedef unsigned int   u32;
typedef __attribute__((ext_vector_type(8))) short short8;
typedef __attribute__((ext_vector_type(4))) float f32x4;

#define NN 256
#define DD 128

__device__ __forceinline__ u16 f2b(float f) {
    union { float f; u32 i; } v; v.f = f;
    u32 x = v.i;
    return (u16)((x + 0x7FFFu + ((x >> 16) & 1u)) >> 16);  // RTN-even
}
__device__ __forceinline__ float b2f(u16 u) {
    union { u32 i; float f; } v; v.i = ((u32)u) << 16; return v.f;
}
__device__ __forceinline__ u32 packbf2(float a, float b) {
    return (u32)f2b(a) | ((u32)f2b(b) << 16);
}
__device__ __forceinline__ float sigm(float z) { return 1.f / (1.f + __expf(-z)); }

// ---------------------------------------------------------------------------
// Kernel 1: transpose 6 f32 weight matrices [d][h] -> bf16 [h][d]
// order in wT: 0=w_left 1=w_lgate 2=w_right 3=w_rgate 4=w_ogate 5=w_out
// ---------------------------------------------------------------------------
__global__ void k_tw(const float* w0, const float* w1, const float* w2,
                     const float* w3, const float* w4, const float* w5,
                     u16* __restrict__ out) {
    int t = blockIdx.x * 256 + threadIdx.x;   // 6*16384 elems
    int mat = t >> 14, idx = t & 16383;
    int h = idx >> 7, d = idx & 127;
    const float* src = (mat == 0) ? w0 : (mat == 1) ? w1 : (mat == 2) ? w2
                      : (mat == 3) ? w3 : (mat == 4) ? w4 : w5;
    out[mat * 16384 + h * 128 + d] = f2b(src[d * 128 + h]);
}

// ---------------------------------------------------------------------------
// Kernel 2: LayerNorm + 5 GEMMs + gating.
// Block = (b, q, ptile): 128 rows (b, p0..p0+127, q).  left/right stored bf16
// in [b, d, q, k=p] layout (k contiguous!).
// ogate: accumulated in LDS as f16 (reusing the xs buffer, dead after the
// A-fragment loads), then bulk-stored as contiguous 512B f32 rows at the end
// -> replaces the former in-loop 64B-granular scattered f32 stores.
// ---------------------------------------------------------------------------
__global__ __launch_bounds__(256, 4)
void k_lngemm(const float* __restrict__ x,
              const float* __restrict__ ng,  const float* __restrict__ nb,
              const u16*   __restrict__ wT,
              const float* __restrict__ bL,  const float* __restrict__ bLG,
              const float* __restrict__ bR,  const float* __restrict__ bRG,
              const float* __restrict__ bOG,
              u16* __restrict__ lT, u16* __restrict__ rT, float* __restrict__ og)
{
    // 32 KiB union: phase 1 = xn bf16 tile, phase 2 = ogate f16 buffer.
    __shared__ uint4 smem4[128 * 16];
    uint4*  xs  = smem4;                 // [row][chunk ^ (row&15)] 16B units
    __half* ogb = (__half*)smem4;        // [p_local 128][h 128] f16 (32768 B)

    const int tid = threadIdx.x;
    const int bx  = blockIdx.x;
    const int b   = bx >> 9;
    const int q   = (bx >> 1) & 255;
    const int p0  = (bx & 1) * 128;

    // ---- LN phase: 16 lanes per row, 16 rows per pass, 8 passes ----
    {
        const int lr = tid >> 4;   // row-within-pass 0..15
        const int c  = tid & 15;   // 8-elem chunk 0..15
        float gg[8], bbv[8];
        {
            float4 g0 = *(const float4*)(ng + c * 8);
            float4 g1 = *(const float4*)(ng + c * 8 + 4);
            float4 b0 = *(const float4*)(nb + c * 8);
            float4 b1 = *(const float4*)(nb + c * 8 + 4);
            gg[0]=g0.x; gg[1]=g0.y; gg[2]=g0.z; gg[3]=g0.w;
            gg[4]=g1.x; gg[5]=g1.y; gg[6]=g1.z; gg[7]=g1.w;
            bbv[0]=b0.x; bbv[1]=b0.y; bbv[2]=b0.z; bbv[3]=b0.w;
            bbv[4]=b1.x; bbv[5]=b1.y; bbv[6]=b1.z; bbv[7]=b1.w;
        }
#pragma unroll
        for (int pass = 0; pass < 8; ++pass) {
            const int r = pass * 16 + lr;                 // local row 0..127
            const long gRow = (long)((b * NN + p0 + r) * NN + q);
            float4 x0 = *(const float4*)(x + gRow * DD + c * 8);
            float4 x1 = *(const float4*)(x + gRow * DD + c * 8 + 4);
            float f[8] = {x0.x, x0.y, x0.z, x0.w, x1.x, x1.y, x1.z, x1.w};
            float s1 = 0.f, s2 = 0.f;
#pragma unroll
            for (int j = 0; j < 8; ++j) { s1 += f[j]; s2 += f[j] * f[j]; }
#pragma unroll
            for (int off = 1; off < 16; off <<= 1) {
                s1 += __shfl_xor(s1, off);
                s2 += __shfl_xor(s2, off);
            }
            const float mu = s1 * (1.f / 128.f);
            const float rs = rsqrtf(s2 * (1.f / 128.f) - mu * mu + 1e-5f);
            uint4 pk;
            pk.x = packbf2((f[0]-mu)*rs*gg[0]+bbv[0], (f[1]-mu)*rs*gg[1]+bbv[1]);
            pk.y = packbf2((f[2]-mu)*rs*gg[2]+bbv[2], (f[3]-mu)*rs*gg[3]+bbv[3]);
            pk.z = packbf2((f[4]-mu)*rs*gg[4]+bbv[4], (f[5]-mu)*rs*gg[5]+bbv[5]);
            pk.w = packbf2((f[6]-mu)*rs*gg[6]+bbv[6], (f[7]-mu)*rs*gg[7]+bbv[7]);
            xs[r * 16 + (c ^ lr)] = pk;                   // xor swizzle
        }
    }
    __syncthreads();

    // ---- GEMM phase: wave w owns rows w*32..w*32+31 (2 m-tiles) ----
    const int w = tid >> 6, lane = tid & 63, quad = lane >> 4, m = lane & 15;

    short8 af[2][4];
#pragma unroll
    for (int mt = 0; mt < 2; ++mt)
#pragma unroll
        for (int s = 0; s < 4; ++s) {
            const int row = w * 32 + mt * 16 + m;
            af[mt][s] = *(const short8*)(xs + row * 16 + ((s * 4 + quad) ^ m));
        }
    __syncthreads();   // xs consumed by all waves -> safe to reuse as ogb

#pragma unroll 2
    for (int nt = 0; nt < 8; ++nt) {
        const int h = nt * 16 + m;
        f32x4 acc[5][2];
        const f32x4 zero = {0.f, 0.f, 0.f, 0.f};
#pragma unroll
        for (int g5 = 0; g5 < 5; ++g5) { acc[g5][0] = zero; acc[g5][1] = zero; }

#pragma unroll
        for (int g5 = 0; g5 < 5; ++g5) {
            const u16* wp = wT + g5 * 16384 + h * 128;
#pragma unroll
            for (int s = 0; s < 4; ++s) {
                short8 bf = *(const short8*)(wp + s * 32 + quad * 8);
                acc[g5][0] = __builtin_amdgcn_mfma_f32_16x16x32_bf16(af[0][s], bf, acc[g5][0], 0, 0, 0);
                acc[g5][1] = __builtin_amdgcn_mfma_f32_16x16x32_bf16(af[1][s], bf, acc[g5][1], 0, 0, 0);
            }
        }
        const float vbl  = bL[h],  vblg = bLG[h];
        const float vbr  = bR[h],  vbrg = bRG[h];
        const float vbog = bOG[h];
#pragma unroll
        for (int mt = 0; mt < 2; ++mt) {
            const int pl = w * 32 + mt * 16 + quad * 4;   // local p base (4 consecutive)
            u16 lp[4], rp[4];
#pragma unroll
            for (int rg = 0; rg < 4; ++rg) {
                float lv = (acc[0][mt][rg] + vbl) * sigm(acc[1][mt][rg] + vblg);
                float rv = (acc[2][mt][rg] + vbr) * sigm(acc[3][mt][rg] + vbrg);
                float ov = sigm(acc[4][mt][rg] + vbog);
                lp[rg] = f2b(lv); rp[rg] = f2b(rv);
                ogb[(pl + rg) * 128 + h] = __float2half(ov);   // f16 in LDS
            }
            const long tbase = ((long)((b * DD + h) * NN + q)) * NN + p0 + pl;
            *(uint2*)(lT + tbase) = *(uint2*)lp;
            *(uint2*)(rT + tbase) = *(uint2*)rp;
        }
    }
    __syncthreads();

    // ---- og bulk store: contiguous 512B f32 per p-row ----
    {
#pragma unroll
        for (int it = 0; it < 16; ++it) {
            const int prow = it * 8 + w * 2 + (lane >> 5);   // local p row
            const int hq   = (lane & 31) * 4;                // 4-elem h chunk
            const __half2* s2 = (const __half2*)(ogb + prow * 128 + hq);
            float2 f01 = __half22float2(s2[0]);
            float2 f23 = __half22float2(s2[1]);
            float4 o = {f01.x, f01.y, f23.x, f23.y};
            *(float4*)(og + ((long)((b * NN + p0 + prow) * NN + q)) * DD + hq) = o;
        }
    }
}

// ---------------------------------------------------------------------------
// Kernel 3: mix.  Per (b,d): C[i,j] = sum_k right[k,i]*left[k,j], both stored
// bf16 [b,d,q,k] so A/B fragments are direct 16B global loads.  Block tile
// 128x128, wave tile 64x64.  Output mx bf16 in [b,d,i,j].
// ---------------------------------------------------------------------------
__global__ __launch_bounds__(256)
void k_mix(const u16* __restrict__ lT, const u16* __restrict__ rT,
           u16* __restrict__ mx)
{
    const int tid = threadIdx.x;
    const int bx  = blockIdx.x;
    const int bd  = bx >> 2;               // b*128 + d
    const int it  = (bx >> 1) & 1, jt = bx & 1;
    const int w = tid >> 6, lane = tid & 63, quad = lane >> 4, m = lane & 15;
    const int ib = it * 128 + (w >> 1) * 64;
    const int jb = jt * 128 + (w & 1) * 64;

    const u16* A  = rT + (long)bd * 65536;   // right: A[i][k]
    const u16* Bp = lT + (long)bd * 65536;   // left : B[k][j] (j-major, k-fastest)

    f32x4 acc[4][4];
    const f32x4 zero = {0.f, 0.f, 0.f, 0.f};
#pragma unroll
    for (int a = 0; a < 4; ++a)
#pragma unroll
        for (int c = 0; c < 4; ++c) acc[a][c] = zero;

#pragma unroll 1
    for (int kc = 0; kc < 8; ++kc) {
        short8 afr[4], bfr[4];
#pragma unroll
        for (int tI = 0; tI < 4; ++tI)
            afr[tI] = *(const short8*)(A + (ib + tI * 16 + m) * 256 + kc * 32 + quad * 8);
#pragma unroll
        for (int tJ = 0; tJ < 4; ++tJ)
            bfr[tJ] = *(const short8*)(Bp + (jb + tJ * 16 + m) * 256 + kc * 32 + quad * 8);
#pragma unroll
        for (int tI = 0; tI < 4; ++tI)
#pragma unroll
            for (int tJ = 0; tJ < 4; ++tJ)
                acc[tI][tJ] = __builtin_amdgcn_mfma_f32_16x16x32_bf16(afr[tI], bfr[tJ], acc[tI][tJ], 0, 0, 0);
    }

#pragma unroll
    for (int tI = 0; tI < 4; ++tI)
#pragma unroll
        for (int tJ = 0; tJ < 4; ++tJ) {
            const int j = jb + tJ * 16 + m;
#pragma unroll
            for (int rg = 0; rg < 4; ++rg) {
                const int i = ib + tI * 16 + quad * 4 + rg;
                mx[(long)bd * 65536 + i * 256 + j] = f2b(acc[tI][tJ][rg]);
            }
        }
}

// ---------------------------------------------------------------------------
// Kernel 4: final.  Block = (b, i, j-tile of 64).  Loads mx[b,:,i,j0:j0+64]
// (coalesced per d-row), LN over d per j, * ogate (f32), then y @ w_outT +
// b_out -> f32 out.  og aliases out: each block reads only its own rows
// before overwriting them (disjoint across blocks).
// Output is staged in LDS (union over the dead m1/ys regions) and written as
// one contiguous 32 KiB block instead of 64B pieces per et-iteration.
// ---------------------------------------------------------------------------
__global__ __launch_bounds__(256)
void k_final(const u16* __restrict__ mx, const float* __restrict__ og,
             const u16* __restrict__ wT5, const float* __restrict__ ong,
             const float* __restrict__ onb, const float* __restrict__ bo_,
             float* __restrict__ out)
{
    // layout: [0,18432)   m1  : uint4 [128][9]  (8 data + 1 pad) bf16
    //         [18432,34816) ys: uint4 [64][16]  bf16 A-frag layout
    //         [34816,35072) mu_s, [35072,35328) rs_s
    //         outs f32 [64 j][128 e] = [0,32768)  -- reuses m1+ys after barrier
    __shared__ __align__(16) unsigned char smem[35328];
    uint4* m1   = (uint4*)smem;
    uint4* ys   = (uint4*)(smem + 18432);
    float* mu_s = (float*)(smem + 34816);
    float* rs_s = (float*)(smem + 35072);
    float* outs = (float*)smem;

    const int tid = threadIdx.x;
    const int bx  = blockIdx.x;
    const int b   = bx >> 10;
    const int i   = (bx >> 2) & 255;
    const int j0  = (bx & 3) * 64;
    const long base = ((long)b * 128) * 65536 + (long)i * 256 + j0;

    {   // load mixed tile: 128 d-rows x 64 j (bf16)
        const int dr = tid >> 3, cc = tid & 7;
#pragma unroll
        for (int pass = 0; pass < 4; ++pass) {
            const int d = pass * 32 + dr;
            m1[d * 9 + cc] = *(const uint4*)(mx + base + (long)d * 65536 + cc * 8);
        }
    }
    __syncthreads();

    if (tid < 128) {   // stats: 2 threads per j
        const int j = tid >> 1, half = tid & 1;
        float s1 = 0.f, s2 = 0.f;
        for (int d = half * 64; d < half * 64 + 64; ++d) {
            float v = b2f(((const u16*)(m1 + d * 9))[j]);
            s1 += v; s2 += v * v;
        }
        s1 += __shfl_xor(s1, 1); s2 += __shfl_xor(s2, 1);
        if (half == 0) {
            const float mu = s1 * (1.f / 128.f);
            mu_s[j] = mu;
            rs_s[j] = rsqrtf(s2 * (1.f / 128.f) - mu * mu + 1e-5f);
        }
    }
    __syncthreads();

    {   // y = (LN(mixed) * ogate) staged bf16 in A-frag layout
        const int j = tid >> 2, c2 = tid & 3;
        const float mu = mu_s[j], rs = rs_s[j];
        const long orow = ((long)((b * NN + i) * NN + j0 + j)) * DD;
#pragma unroll
        for (int s4 = 0; s4 < 4; ++s4) {
            const int ch = c2 * 4 + s4;          // d chunk 0..15
            float4 o0 = *(const float4*)(og + orow + ch * 8);
            float4 o1 = *(const float4*)(og + orow + ch * 8 + 4);
            float4 g0 = *(const float4*)(ong + ch * 8);
            float4 g1 = *(const float4*)(ong + ch * 8 + 4);
            float4 n0 = *(const float4*)(onb + ch * 8);
            float4 n1 = *(const float4*)(onb + ch * 8 + 4);
            float ov[8] = {o0.x,o0.y,o0.z,o0.w,o1.x,o1.y,o1.z,o1.w};
            float gv[8] = {g0.x,g0.y,g0.z,g0.w,g1.x,g1.y,g1.z,g1.w};
            float bv[8] = {n0.x,n0.y,n0.z,n0.w,n1.x,n1.y,n1.z,n1.w};
            u16 yy[8];
#pragma unroll
            for (int jj = 0; jj < 8; ++jj) {
                const int d = ch * 8 + jj;
                const float v = b2f(((const u16*)(m1 + d * 9))[j]);
                yy[jj] = f2b(((v - mu) * rs * gv[jj] + bv[jj]) * ov[jj]);
            }
            ys[j * 16 + (ch ^ (j & 15))] = *(uint4*)yy;
        }
    }
    __syncthreads();

    // GEMM: 64 j-rows x 128 e, K = 128.  wave w -> m-tile w.
    const int w = tid >> 6, lane = tid & 63, quad = lane >> 4, m = lane & 15;
    short8 afr[4];
#pragma unroll
    for (int s = 0; s < 4; ++s)
        afr[s] = *(const short8*)(ys + (w * 16 + m) * 16 + ((s * 4 + quad) ^ m));
    __syncthreads();   // ys consumed -> safe to reuse LDS as outs

#pragma unroll 1
    for (int et = 0; et < 8; ++et) {
        f32x4 acc = {0.f, 0.f, 0.f, 0.f};
        const u16* wp = wT5 + (et * 16 + m) * 128;
#pragma unroll
        for (int s = 0; s < 4; ++s) {
            short8 bfr = *(const short8*)(wp + s * 32 + quad * 8);
            acc = __builtin_amdgcn_mfma_f32_16x16x32_bf16(afr[s], bfr, acc, 0, 0, 0);
        }
        const int e = et * 16 + m;
        const float bo = bo_[e];
#pragma unroll
        for (int rg = 0; rg < 4; ++rg) {
            const int jl = w * 16 + quad * 4 + rg;
            outs[jl * 128 + e] = acc[rg] + bo;
        }
    }
    __syncthreads();

    {   // bulk store: 64 rows x 512B, fully contiguous 32 KiB per block
#pragma unroll
        for (int it2 = 0; it2 < 8; ++it2) {
            const int jl = it2 * 8 + w * 2 + (lane >> 5);
            const int e4 = (lane & 31) * 4;
            float4 o = *(const float4*)(outs + jl * 128 + e4);
            *(float4*)(out + ((long)((b * NN + i) * NN + j0 + jl)) * DD + e4) = o;
        }
    }
}

// ---------------------------------------------------------------------------
extern "C" void kernel_launch(void* const* d_in, const int* in_sizes, int n_in,
                              void* d_out, int out_size, void* d_ws, size_t ws_size,
                              hipStream_t stream) {
    const float* x   = (const float*)d_in[0];
    const float* ng  = (const float*)d_in[1];
    const float* nb  = (const float*)d_in[2];
    const float* wl  = (const float*)d_in[3];
    const float* bl  = (const float*)d_in[4];
    const float* wr  = (const float*)d_in[5];
    const float* br  = (const float*)d_in[6];
    const float* wlg = (const float*)d_in[7];
    const float* blg = (const float*)d_in[8];
    const float* wrg = (const float*)d_in[9];
    const float* brg = (const float*)d_in[10];
    const float* wog = (const float*)d_in[11];
    const float* bog = (const float*)d_in[12];
    const float* ong = (const float*)d_in[13];
    const float* onb = (const float*)d_in[14];
    const float* wo  = (const float*)d_in[15];
    const float* bo  = (const float*)d_in[16];

    u16* ws = (u16*)d_ws;
    const long BIG = 33554432;          // 4*128*256*256 elements
    // Workspace: lT, rT, mx (bf16, 3 x 64 MiB) + 192 KiB bf16 weights.
    // og (f32) aliases d_out: k_lngemm writes it, k_final reads each block's
    // own rows before overwriting them with the f32 output.
    const size_t need = (size_t)(3 * BIG + 6 * 16384) * sizeof(u16);
    if (ws_size < need) return;  // clean failure instead of OOB fault

    u16* lT = ws;                        // bf16 [b,d,q,k]
    u16* rT = lT + BIG;                  // bf16 [b,d,q,k]
    u16* mx = rT + BIG;                  // bf16 [b,d,i,j]
    u16* wT = mx + BIG;                  // bf16, 6 x 128x128 transposed weights
    float* og = (float*)d_out;           // f32 [(b,i,j)][h]  (aliases d_out)

    k_tw<<<384, 256, 0, stream>>>(wl, wlg, wr, wrg, wog, wo, wT);
    k_lngemm<<<2048, 256, 0, stream>>>(x, ng, nb, wT, bl, blg, br, brg, bog, lT, rT, og);
    k_mix<<<2048, 256, 0, stream>>>(lT, rT, mx);
    k_final<<<4096, 256, 0, stream>>>(mx, og, wT + 5 * 16384, ong, onb, bo, (float*)d_out);
}

// Round 2
// 535.182 us; speedup vs baseline: 1.2076x; 1.1534x over previous
//
#include <hip/hip_runtime.h>
#include <hip/hip_fp16.h>

typedef unsigned short u16;
typedef unsigned int   u32;
typedef __attribute__((ext_vector_type(8))) short short8;
typedef __attribute__((ext_vector_type(4))) float f32x4;

#define NN 256
#define DD 128

__device__ __forceinline__ u16 f2b(float f) {
    union { float f; u32 i; } v; v.f = f;
    u32 x = v.i;
    return (u16)((x + 0x7FFFu + ((x >> 16) & 1u)) >> 16);  // RTN-even
}
__device__ __forceinline__ float b2f(u16 u) {
    union { u32 i; float f; } v; v.i = ((u32)u) << 16; return v.f;
}
__device__ __forceinline__ u32 packbf2(float a, float b) {
    return (u32)f2b(a) | ((u32)f2b(b) << 16);
}
__device__ __forceinline__ float sigm(float z) { return 1.f / (1.f + __expf(-z)); }

// ---------------------------------------------------------------------------
// Kernel 1: repack 6 f32 weight matrices [d][h] into bf16 MFMA B-fragment
// order: frag[(mat*8+nt)*4+s][lane][8] where lane=(quad<<4)|m holds
// w[d = s*32+quad*8 .. +8][h = nt*16+m].  Every weight load in the GEMM
// kernels becomes base + lane*16B -> perfectly coalesced.
// order: 0=w_left 1=w_lgate 2=w_right 3=w_rgate 4=w_ogate 5=w_out
// ---------------------------------------------------------------------------
__global__ void k_tw(const float* w0, const float* w1, const float* w2,
                     const float* w3, const float* w4, const float* w5,
                     u16* __restrict__ out) {
    int t = blockIdx.x * 256 + threadIdx.x;   // 12288 threads, 8 outputs each
    int mat = t >> 11, idx = t & 2047;        // idx = (nt*4+s)*64 + lane
    int lane = idx & 63;
    int s    = (idx >> 6) & 3;
    int nt   = idx >> 8;
    int m = lane & 15, quad = lane >> 4;
    int h  = nt * 16 + m;
    int d0 = s * 32 + quad * 8;
    const float* src = (mat == 0) ? w0 : (mat == 1) ? w1 : (mat == 2) ? w2
                      : (mat == 3) ? w3 : (mat == 4) ? w4 : w5;
    u16 vals[8];
#pragma unroll
    for (int j = 0; j < 8; ++j) vals[j] = f2b(src[(d0 + j) * 128 + h]);
    *(uint4*)(out + (t << 3)) = *(uint4*)vals;   // t*8 = mat*16384 + idx*8
}

// ---------------------------------------------------------------------------
// Kernel 2: LayerNorm + 5 GEMMs + gating.
// Block = (b, q, ptile): 128 rows (b, p0..p0+127, q).  left/right stored bf16
// in [b, d, q, k=p] layout (k contiguous!).
// Weights read in fragment order (coalesced).  ogate accumulated f16 in LDS
// (reusing xs), bulk-stored as contiguous 512B f32 rows.
// ---------------------------------------------------------------------------
__global__ __launch_bounds__(256, 4)
void k_lngemm(const float* __restrict__ x,
              const float* __restrict__ ng,  const float* __restrict__ nb,
              const u16*   __restrict__ wT,
              const float* __restrict__ bL,  const float* __restrict__ bLG,
              const float* __restrict__ bR,  const float* __restrict__ bRG,
              const float* __restrict__ bOG,
              u16* __restrict__ lT, u16* __restrict__ rT, float* __restrict__ og)
{
    // 32 KiB union: phase 1 = xn bf16 tile, phase 2 = ogate f16 buffer.
    __shared__ uint4 smem4[128 * 16];
    uint4*  xs  = smem4;                 // [row][chunk ^ (row&15)] 16B units
    __half* ogb = (__half*)smem4;        // [p_local 128][h 128] f16 (32768 B)

    const int tid = threadIdx.x;
    const int bx  = blockIdx.x;
    const int b   = bx >> 9;
    const int q   = (bx >> 1) & 255;
    const int p0  = (bx & 1) * 128;

    // ---- LN phase: 16 lanes per row, 16 rows per pass, 8 passes ----
    {
        const int lr = tid >> 4;   // row-within-pass 0..15
        const int c  = tid & 15;   // 8-elem chunk 0..15
        float gg[8], bbv[8];
        {
            float4 g0 = *(const float4*)(ng + c * 8);
            float4 g1 = *(const float4*)(ng + c * 8 + 4);
            float4 b0 = *(const float4*)(nb + c * 8);
            float4 b1 = *(const float4*)(nb + c * 8 + 4);
            gg[0]=g0.x; gg[1]=g0.y; gg[2]=g0.z; gg[3]=g0.w;
            gg[4]=g1.x; gg[5]=g1.y; gg[6]=g1.z; gg[7]=g1.w;
            bbv[0]=b0.x; bbv[1]=b0.y; bbv[2]=b0.z; bbv[3]=b0.w;
            bbv[4]=b1.x; bbv[5]=b1.y; bbv[6]=b1.z; bbv[7]=b1.w;
        }
#pragma unroll
        for (int pass = 0; pass < 8; ++pass) {
            const int r = pass * 16 + lr;                 // local row 0..127
            const long gRow = (long)((b * NN + p0 + r) * NN + q);
            float4 x0 = *(const float4*)(x + gRow * DD + c * 8);
            float4 x1 = *(const float4*)(x + gRow * DD + c * 8 + 4);
            float f[8] = {x0.x, x0.y, x0.z, x0.w, x1.x, x1.y, x1.z, x1.w};
            float s1 = 0.f, s2 = 0.f;
#pragma unroll
            for (int j = 0; j < 8; ++j) { s1 += f[j]; s2 += f[j] * f[j]; }
#pragma unroll
            for (int off = 1; off < 16; off <<= 1) {
                s1 += __shfl_xor(s1, off);
                s2 += __shfl_xor(s2, off);
            }
            const float mu = s1 * (1.f / 128.f);
            const float rs = rsqrtf(s2 * (1.f / 128.f) - mu * mu + 1e-5f);
            uint4 pk;
            pk.x = packbf2((f[0]-mu)*rs*gg[0]+bbv[0], (f[1]-mu)*rs*gg[1]+bbv[1]);
            pk.y = packbf2((f[2]-mu)*rs*gg[2]+bbv[2], (f[3]-mu)*rs*gg[3]+bbv[3]);
            pk.z = packbf2((f[4]-mu)*rs*gg[4]+bbv[4], (f[5]-mu)*rs*gg[5]+bbv[5]);
            pk.w = packbf2((f[6]-mu)*rs*gg[6]+bbv[6], (f[7]-mu)*rs*gg[7]+bbv[7]);
            xs[r * 16 + (c ^ lr)] = pk;                   // xor swizzle
        }
    }
    __syncthreads();

    // ---- GEMM phase: wave w owns rows w*32..w*32+31 (2 m-tiles) ----
    const int w = tid >> 6, lane = tid & 63, quad = lane >> 4, m = lane & 15;

    short8 af[2][4];
#pragma unroll
    for (int mt = 0; mt < 2; ++mt)
#pragma unroll
        for (int s = 0; s < 4; ++s) {
            const int row = w * 32 + mt * 16 + m;
            af[mt][s] = *(const short8*)(xs + row * 16 + ((s * 4 + quad) ^ m));
        }
    __syncthreads();   // xs consumed by all waves -> safe to reuse as ogb

#pragma unroll 2
    for (int nt = 0; nt < 8; ++nt) {
        const int h = nt * 16 + m;
        f32x4 acc[5][2];
        const f32x4 zero = {0.f, 0.f, 0.f, 0.f};
#pragma unroll
        for (int g5 = 0; g5 < 5; ++g5) { acc[g5][0] = zero; acc[g5][1] = zero; }

#pragma unroll
        for (int g5 = 0; g5 < 5; ++g5) {
            // fragment-ordered weights: coalesced lane*16B loads
            const u16* wfb = wT + ((((g5 << 3) + nt) << 2) << 9) + (lane << 3);
#pragma unroll
            for (int s = 0; s < 4; ++s) {
                short8 bf = *(const short8*)(wfb + (s << 9));
                acc[g5][0] = __builtin_amdgcn_mfma_f32_16x16x32_bf16(af[0][s], bf, acc[g5][0], 0, 0, 0);
                acc[g5][1] = __builtin_amdgcn_mfma_f32_16x16x32_bf16(af[1][s], bf, acc[g5][1], 0, 0, 0);
            }
        }
        const float vbl  = bL[h],  vblg = bLG[h];
        const float vbr  = bR[h],  vbrg = bRG[h];
        const float vbog = bOG[h];
#pragma unroll
        for (int mt = 0; mt < 2; ++mt) {
            const int pl = w * 32 + mt * 16 + quad * 4;   // local p base (4 consecutive)
            u16 lp[4], rp[4];
#pragma unroll
            for (int rg = 0; rg < 4; ++rg) {
                float lv = (acc[0][mt][rg] + vbl) * sigm(acc[1][mt][rg] + vblg);
                float rv = (acc[2][mt][rg] + vbr) * sigm(acc[3][mt][rg] + vbrg);
                float ov = sigm(acc[4][mt][rg] + vbog);
                lp[rg] = f2b(lv); rp[rg] = f2b(rv);
                ogb[(pl + rg) * 128 + h] = __float2half(ov);   // f16 in LDS
            }
            const long tbase = ((long)((b * DD + h) * NN + q)) * NN + p0 + pl;
            *(uint2*)(lT + tbase) = *(uint2*)lp;
            *(uint2*)(rT + tbase) = *(uint2*)rp;
        }
    }
    __syncthreads();

    // ---- og bulk store: contiguous 512B f32 per p-row ----
    {
#pragma unroll
        for (int it = 0; it < 16; ++it) {
            const int prow = it * 8 + w * 2 + (lane >> 5);   // local p row
            const int hq   = (lane & 31) * 4;                // 4-elem h chunk
            const __half2* s2 = (const __half2*)(ogb + prow * 128 + hq);
            float2 f01 = __half22float2(s2[0]);
            float2 f23 = __half22float2(s2[1]);
            float4 o = {f01.x, f01.y, f23.x, f23.y};
            *(float4*)(og + ((long)((b * NN + p0 + prow) * NN + q)) * DD + hq) = o;
        }
    }
}

// ---------------------------------------------------------------------------
// Kernel 3: mix.  Per (b,d): C[i,j] = sum_k right[k,i]*left[k,j], both stored
// bf16 [b,d,q,k] so A/B fragments are direct 16B global loads.  Block tile
// 128x128, wave tile 64x64.  Output mx bf16 in [b,d,i,j].
// Operands SWAPPED in the MFMA (mfma(b,a)) so the D-tile is transposed:
// lane's 4 acc regs = 4 consecutive j -> uint2 stores (4x fewer store instrs).
// ---------------------------------------------------------------------------
__global__ __launch_bounds__(256)
void k_mix(const u16* __restrict__ lT, const u16* __restrict__ rT,
           u16* __restrict__ mx)
{
    const int tid = threadIdx.x;
    const int bx  = blockIdx.x;
    const int bd  = bx >> 2;               // b*128 + d
    const int it  = (bx >> 1) & 1, jt = bx & 1;
    const int w = tid >> 6, lane = tid & 63, quad = lane >> 4, m = lane & 15;
    const int ib = it * 128 + (w >> 1) * 64;
    const int jb = jt * 128 + (w & 1) * 64;

    const u16* A  = rT + (long)bd * 65536;   // right: A[i][k]
    const u16* Bp = lT + (long)bd * 65536;   // left : B[k][j] (j-major, k-fastest)

    f32x4 acc[4][4];
    const f32x4 zero = {0.f, 0.f, 0.f, 0.f};
#pragma unroll
    for (int a = 0; a < 4; ++a)
#pragma unroll
        for (int c = 0; c < 4; ++c) acc[a][c] = zero;

#pragma unroll 1
    for (int kc = 0; kc < 8; ++kc) {
        short8 afr[4], bfr[4];
#pragma unroll
        for (int tI = 0; tI < 4; ++tI)
            afr[tI] = *(const short8*)(A + (ib + tI * 16 + m) * 256 + kc * 32 + quad * 8);
#pragma unroll
        for (int tJ = 0; tJ < 4; ++tJ)
            bfr[tJ] = *(const short8*)(Bp + (jb + tJ * 16 + m) * 256 + kc * 32 + quad * 8);
#pragma unroll
        for (int tI = 0; tI < 4; ++tI)
#pragma unroll
            for (int tJ = 0; tJ < 4; ++tJ)
                acc[tI][tJ] = __builtin_amdgcn_mfma_f32_16x16x32_bf16(bfr[tJ], afr[tI], acc[tI][tJ], 0, 0, 0);
    }

    // D is transposed: col = i = m, row = j = quad*4+rg -> j-contiguous stores
#pragma unroll
    for (int tI = 0; tI < 4; ++tI)
#pragma unroll
        for (int tJ = 0; tJ < 4; ++tJ) {
            const int i = ib + tI * 16 + m;
            const int j = jb + tJ * 16 + quad * 4;
            u16 vv[4];
#pragma unroll
            for (int rg = 0; rg < 4; ++rg) vv[rg] = f2b(acc[tI][tJ][rg]);
            *(uint2*)(mx + (long)bd * 65536 + i * 256 + j) = *(uint2*)vv;
        }
}

// ---------------------------------------------------------------------------
// Kernel 4: final.  Block = (b, i, j-tile of 64).  Loads mx[b,:,i,j0:j0+64]
// (coalesced per d-row), LN over d per j, * ogate (f32), then y @ w_outT +
// b_out -> f32 out.  og aliases out: each block reads only its own rows
// before overwriting them (disjoint across blocks).
// w_out read in fragment order (coalesced).  Output staged in LDS and
// written as one contiguous 32 KiB block.
// ---------------------------------------------------------------------------
__global__ __launch_bounds__(256)
void k_final(const u16* __restrict__ mx, const float* __restrict__ og,
             const u16* __restrict__ wT5, const float* __restrict__ ong,
             const float* __restrict__ onb, const float* __restrict__ bo_,
             float* __restrict__ out)
{
    // layout: [0,18432)   m1  : uint4 [128][9]  (8 data + 1 pad) bf16
    //         [18432,34816) ys: uint4 [64][16]  bf16 A-frag layout
    //         [34816,35072) mu_s, [35072,35328) rs_s
    //         outs f32 [64 j][128 e] = [0,32768)  -- reuses m1+ys after barrier
    __shared__ __align__(16) unsigned char smem[35328];
    uint4* m1   = (uint4*)smem;
    uint4* ys   = (uint4*)(smem + 18432);
    float* mu_s = (float*)(smem + 34816);
    float* rs_s = (float*)(smem + 35072);
    float* outs = (float*)smem;

    const int tid = threadIdx.x;
    const int bx  = blockIdx.x;
    const int b   = bx >> 10;
    const int i   = (bx >> 2) & 255;
    const int j0  = (bx & 3) * 64;
    const long base = ((long)b * 128) * 65536 + (long)i * 256 + j0;

    {   // load mixed tile: 128 d-rows x 64 j (bf16)
        const int dr = tid >> 3, cc = tid & 7;
#pragma unroll
        for (int pass = 0; pass < 4; ++pass) {
            const int d = pass * 32 + dr;
            m1[d * 9 + cc] = *(const uint4*)(mx + base + (long)d * 65536 + cc * 8);
        }
    }
    __syncthreads();

    if (tid < 128) {   // stats: 2 threads per j
        const int j = tid >> 1, half = tid & 1;
        float s1 = 0.f, s2 = 0.f;
        for (int d = half * 64; d < half * 64 + 64; ++d) {
            float v = b2f(((const u16*)(m1 + d * 9))[j]);
            s1 += v; s2 += v * v;
        }
        s1 += __shfl_xor(s1, 1); s2 += __shfl_xor(s2, 1);
        if (half == 0) {
            const float mu = s1 * (1.f / 128.f);
            mu_s[j] = mu;
            rs_s[j] = rsqrtf(s2 * (1.f / 128.f) - mu * mu + 1e-5f);
        }
    }
    __syncthreads();

    {   // y = (LN(mixed) * ogate) staged bf16 in A-frag layout
        const int j = tid >> 2, c2 = tid & 3;
        const float mu = mu_s[j], rs = rs_s[j];
        const long orow = ((long)((b * NN + i) * NN + j0 + j)) * DD;
#pragma unroll
        for (int s4 = 0; s4 < 4; ++s4) {
            const int ch = c2 * 4 + s4;          // d chunk 0..15
            float4 o0 = *(const float4*)(og + orow + ch * 8);
            float4 o1 = *(const float4*)(og + orow + ch * 8 + 4);
            float4 g0 = *(const float4*)(ong + ch * 8);
            float4 g1 = *(const float4*)(ong + ch * 8 + 4);
            float4 n0 = *(const float4*)(onb + ch * 8);
            float4 n1 = *(const float4*)(onb + ch * 8 + 4);
            float ov[8] = {o0.x,o0.y,o0.z,o0.w,o1.x,o1.y,o1.z,o1.w};
            float gv[8] = {g0.x,g0.y,g0.z,g0.w,g1.x,g1.y,g1.z,g1.w};
            float bv[8] = {n0.x,n0.y,n0.z,n0.w,n1.x,n1.y,n1.z,n1.w};
            u16 yy[8];
#pragma unroll
            for (int jj = 0; jj < 8; ++jj) {
                const int d = ch * 8 + jj;
                const float v = b2f(((const u16*)(m1 + d * 9))[j]);
                yy[jj] = f2b(((v - mu) * rs * gv[jj] + bv[jj]) * ov[jj]);
            }
            ys[j * 16 + (ch ^ (j & 15))] = *(uint4*)yy;
        }
    }
    __syncthreads();

    // GEMM: 64 j-rows x 128 e, K = 128.  wave w -> m-tile w.
    const int w = tid >> 6, lane = tid & 63, quad = lane >> 4, m = lane & 15;
    short8 afr[4];
#pragma unroll
    for (int s = 0; s < 4; ++s)
        afr[s] = *(const short8*)(ys + (w * 16 + m) * 16 + ((s * 4 + quad) ^ m));
    __syncthreads();   // ys consumed -> safe to reuse LDS as outs

#pragma unroll 1
    for (int et = 0; et < 8; ++et) {
        f32x4 acc = {0.f, 0.f, 0.f, 0.f};
#pragma unroll
        for (int s = 0; s < 4; ++s) {
            // fragment-ordered w_out: coalesced lane*16B loads
            short8 bfr = *(const short8*)(wT5 + (((et << 2) + s) << 9) + (lane << 3));
            acc = __builtin_amdgcn_mfma_f32_16x16x32_bf16(afr[s], bfr, acc, 0, 0, 0);
        }
        const int e = et * 16 + m;
        const float bo = bo_[e];
#pragma unroll
        for (int rg = 0; rg < 4; ++rg) {
            const int jl = w * 16 + quad * 4 + rg;
            outs[jl * 128 + e] = acc[rg] + bo;
        }
    }
    __syncthreads();

    {   // bulk store: 64 rows x 512B, fully contiguous 32 KiB per block
#pragma unroll
        for (int it2 = 0; it2 < 8; ++it2) {
            const int jl = it2 * 8 + w * 2 + (lane >> 5);
            const int e4 = (lane & 31) * 4;
            float4 o = *(const float4*)(outs + jl * 128 + e4);
            *(float4*)(out + ((long)((b * NN + i) * NN + j0 + jl)) * DD + e4) = o;
        }
    }
}

// ---------------------------------------------------------------------------
extern "C" void kernel_launch(void* const* d_in, const int* in_sizes, int n_in,
                              void* d_out, int out_size, void* d_ws, size_t ws_size,
                              hipStream_t stream) {
    const float* x   = (const float*)d_in[0];
    const float* ng  = (const float*)d_in[1];
    const float* nb  = (const float*)d_in[2];
    const float* wl  = (const float*)d_in[3];
    const float* bl  = (const float*)d_in[4];
    const float* wr  = (const float*)d_in[5];
    const float* br  = (const float*)d_in[6];
    const float* wlg = (const float*)d_in[7];
    const float* blg = (const float*)d_in[8];
    const float* wrg = (const float*)d_in[9];
    const float* brg = (const float*)d_in[10];
    const float* wog = (const float*)d_in[11];
    const float* bog = (const float*)d_in[12];
    const float* ong = (const float*)d_in[13];
    const float* onb = (const float*)d_in[14];
    const float* wo  = (const float*)d_in[15];
    const float* bo  = (const float*)d_in[16];

    u16* ws = (u16*)d_ws;
    const long BIG = 33554432;          // 4*128*256*256 elements
    // Workspace: lT, rT, mx (bf16, 3 x 64 MiB) + 192 KiB bf16 weights.
    // og (f32) aliases d_out: k_lngemm writes it, k_final reads each block's
    // own rows before overwriting them with the f32 output.
    const size_t need = (size_t)(3 * BIG + 6 * 16384) * sizeof(u16);
    if (ws_size < need) return;  // clean failure instead of OOB fault

    u16* lT = ws;                        // bf16 [b,d,q,k]
    u16* rT = lT + BIG;                  // bf16 [b,d,q,k]
    u16* mx = rT + BIG;                  // bf16 [b,d,i,j]
    u16* wT = mx + BIG;                  // bf16, 6 mats in MFMA fragment order
    float* og = (float*)d_out;           // f32 [(b,i,j)][h]  (aliases d_out)

    k_tw<<<48, 256, 0, stream>>>(wl, wlg, wr, wrg, wog, wo, wT);
    k_lngemm<<<2048, 256, 0, stream>>>(x, ng, nb, wT, bl, blg, br, brg, bog, lT, rT, og);
    k_mix<<<2048, 256, 0, stream>>>(lT, rT, mx);
    k_final<<<4096, 256, 0, stream>>>(mx, og, wT + 5 * 16384, ong, onb, bo, (float*)d_out);
}

// Round 3
// 519.212 us; speedup vs baseline: 1.2447x; 1.0308x over previous
//
#include <hip/hip_runtime.h>
#include <hip/hip_fp16.h>

typedef unsigned short u16;
typedef unsigned int   u32;
typedef __attribute__((ext_vector_type(8))) short short8;
typedef __attribute__((ext_vector_type(4))) float f32x4;

#define NN 256
#define DD 128

__device__ __forceinline__ u16 f2b(float f) {
    union { float f; u32 i; } v; v.f = f;
    u32 x = v.i;
    return (u16)((x + 0x7FFFu + ((x >> 16) & 1u)) >> 16);  // RTN-even
}
__device__ __forceinline__ float b2f(u16 u) {
    union { u32 i; float f; } v; v.i = ((u32)u) << 16; return v.f;
}
// HW packed f32->bf16 (RNE), 1 instr for 2 values: lo in [15:0], hi in [31:16]
__device__ __forceinline__ u32 cvtpk(float lo, float hi) {
    u32 r;
    asm("v_cvt_pk_bf16_f32 %0, %1, %2" : "=v"(r) : "v"(lo), "v"(hi));
    return r;
}
__device__ __forceinline__ float sigm(float z) { return 1.f / (1.f + __expf(-z)); }

// ---------------------------------------------------------------------------
// Kernel 1: repack 6 f32 weight matrices [d][h] into bf16 MFMA B-fragment
// order: frag[(mat*8+nt)*4+s][lane][8] where lane=(quad<<4)|m holds
// w[d = s*32+quad*8 .. +8][h = nt*16+m].  Every weight load in the GEMM
// kernels becomes base + lane*16B -> perfectly coalesced.
// order: 0=w_left 1=w_lgate 2=w_right 3=w_rgate 4=w_ogate 5=w_out
// ---------------------------------------------------------------------------
__global__ void k_tw(const float* w0, const float* w1, const float* w2,
                     const float* w3, const float* w4, const float* w5,
                     u16* __restrict__ out) {
    int t = blockIdx.x * 256 + threadIdx.x;   // 12288 threads, 8 outputs each
    int mat = t >> 11, idx = t & 2047;        // idx = (nt*4+s)*64 + lane
    int lane = idx & 63;
    int s    = (idx >> 6) & 3;
    int nt   = idx >> 8;
    int m = lane & 15, quad = lane >> 4;
    int h  = nt * 16 + m;
    int d0 = s * 32 + quad * 8;
    const float* src = (mat == 0) ? w0 : (mat == 1) ? w1 : (mat == 2) ? w2
                      : (mat == 3) ? w3 : (mat == 4) ? w4 : w5;
    u16 vals[8];
#pragma unroll
    for (int j = 0; j < 8; ++j) vals[j] = f2b(src[(d0 + j) * 128 + h]);
    *(uint4*)(out + (t << 3)) = *(uint4*)vals;   // t*8 = mat*16384 + idx*8
}

// ---------------------------------------------------------------------------
// Kernel 2: LayerNorm + 5 GEMMs + gating.
// Block = (b, q, ptile): 128 rows (b, p0..p0+127, q).
// left/right stored bf16 in MFMA-FRAGMENT order:
//   [bd][qt=q>>4][pc=p>>5][qm=q&15][pq=(p>>3)&3][pr=p&7]
// (row-major 16x32 bf16 subtile per (qt,pc)) so k_mix fragment loads are
// dense 1KB runs.  Store scatter here is unchanged (16 x 32B segments).
// Weights read in fragment order (coalesced).  ogate accumulated f16 in LDS
// (reusing xs), bulk-stored as contiguous 512B f32 rows.
// ---------------------------------------------------------------------------
__global__ __launch_bounds__(256, 4)
void k_lngemm(const float* __restrict__ x,
              const float* __restrict__ ng,  const float* __restrict__ nb,
              const u16*   __restrict__ wT,
              const float* __restrict__ bL,  const float* __restrict__ bLG,
              const float* __restrict__ bR,  const float* __restrict__ bRG,
              const float* __restrict__ bOG,
              u16* __restrict__ lT, u16* __restrict__ rT, float* __restrict__ og)
{
    // 32 KiB union: phase 1 = xn bf16 tile, phase 2 = ogate f16 buffer.
    __shared__ uint4 smem4[128 * 16];
    uint4*  xs  = smem4;                 // [row][chunk ^ (row&15)] 16B units
    __half* ogb = (__half*)smem4;        // [p_local 128][h 128] f16 (32768 B)

    const int tid = threadIdx.x;
    const int bx  = blockIdx.x;
    const int b   = bx >> 9;
    const int q   = (bx >> 1) & 255;
    const int p0  = (bx & 1) * 128;

    // ---- LN phase: 16 lanes per row, 16 rows per pass, 8 passes ----
    {
        const int lr = tid >> 4;   // row-within-pass 0..15
        const int c  = tid & 15;   // 8-elem chunk 0..15
        float gg[8], bbv[8];
        {
            float4 g0 = *(const float4*)(ng + c * 8);
            float4 g1 = *(const float4*)(ng + c * 8 + 4);
            float4 b0 = *(const float4*)(nb + c * 8);
            float4 b1 = *(const float4*)(nb + c * 8 + 4);
            gg[0]=g0.x; gg[1]=g0.y; gg[2]=g0.z; gg[3]=g0.w;
            gg[4]=g1.x; gg[5]=g1.y; gg[6]=g1.z; gg[7]=g1.w;
            bbv[0]=b0.x; bbv[1]=b0.y; bbv[2]=b0.z; bbv[3]=b0.w;
            bbv[4]=b1.x; bbv[5]=b1.y; bbv[6]=b1.z; bbv[7]=b1.w;
        }
#pragma unroll
        for (int pass = 0; pass < 8; ++pass) {
            const int r = pass * 16 + lr;                 // local row 0..127
            const long gRow = (long)((b * NN + p0 + r) * NN + q);
            float4 x0 = *(const float4*)(x + gRow * DD + c * 8);
            float4 x1 = *(const float4*)(x + gRow * DD + c * 8 + 4);
            float f[8] = {x0.x, x0.y, x0.z, x0.w, x1.x, x1.y, x1.z, x1.w};
            float s1 = 0.f, s2 = 0.f;
#pragma unroll
            for (int j = 0; j < 8; ++j) { s1 += f[j]; s2 += f[j] * f[j]; }
#pragma unroll
            for (int off = 1; off < 16; off <<= 1) {
                s1 += __shfl_xor(s1, off);
                s2 += __shfl_xor(s2, off);
            }
            const float mu = s1 * (1.f / 128.f);
            const float rs = rsqrtf(s2 * (1.f / 128.f) - mu * mu + 1e-5f);
            uint4 pk;
            pk.x = cvtpk((f[0]-mu)*rs*gg[0]+bbv[0], (f[1]-mu)*rs*gg[1]+bbv[1]);
            pk.y = cvtpk((f[2]-mu)*rs*gg[2]+bbv[2], (f[3]-mu)*rs*gg[3]+bbv[3]);
            pk.z = cvtpk((f[4]-mu)*rs*gg[4]+bbv[4], (f[5]-mu)*rs*gg[5]+bbv[5]);
            pk.w = cvtpk((f[6]-mu)*rs*gg[6]+bbv[6], (f[7]-mu)*rs*gg[7]+bbv[7]);
            xs[r * 16 + (c ^ lr)] = pk;                   // xor swizzle
        }
    }
    __syncthreads();

    // ---- GEMM phase: wave w owns rows w*32..w*32+31 (2 m-tiles) ----
    const int w = tid >> 6, lane = tid & 63, quad = lane >> 4, m = lane & 15;

    short8 af[2][4];
#pragma unroll
    for (int mt = 0; mt < 2; ++mt)
#pragma unroll
        for (int s = 0; s < 4; ++s) {
            const int row = w * 32 + mt * 16 + m;
            af[mt][s] = *(const short8*)(xs + row * 16 + ((s * 4 + quad) ^ m));
        }
    __syncthreads();   // xs consumed by all waves -> safe to reuse as ogb

    const int qt = q >> 4, qm = q & 15;

#pragma unroll 2
    for (int nt = 0; nt < 8; ++nt) {
        const int h = nt * 16 + m;
        f32x4 acc[5][2];
        const f32x4 zero = {0.f, 0.f, 0.f, 0.f};
#pragma unroll
        for (int g5 = 0; g5 < 5; ++g5) { acc[g5][0] = zero; acc[g5][1] = zero; }

#pragma unroll
        for (int g5 = 0; g5 < 5; ++g5) {
            // fragment-ordered weights: coalesced lane*16B loads
            const u16* wfb = wT + ((((g5 << 3) + nt) << 2) << 9) + (lane << 3);
#pragma unroll
            for (int s = 0; s < 4; ++s) {
                short8 bf = *(const short8*)(wfb + (s << 9));
                acc[g5][0] = __builtin_amdgcn_mfma_f32_16x16x32_bf16(af[0][s], bf, acc[g5][0], 0, 0, 0);
                acc[g5][1] = __builtin_amdgcn_mfma_f32_16x16x32_bf16(af[1][s], bf, acc[g5][1], 0, 0, 0);
            }
        }
        const float vbl  = bL[h],  vblg = bLG[h];
        const float vbr  = bR[h],  vbrg = bRG[h];
        const float vbog = bOG[h];
        const long fb = ((long)(b * 128 + h) * 16 + qt) * 8;
#pragma unroll
        for (int mt = 0; mt < 2; ++mt) {
            const int pl = w * 32 + mt * 16 + quad * 4;   // local p base (4 consecutive)
            float lvf[4], rvf[4];
#pragma unroll
            for (int rg = 0; rg < 4; ++rg) {
                lvf[rg] = (acc[0][mt][rg] + vbl) * sigm(acc[1][mt][rg] + vblg);
                rvf[rg] = (acc[2][mt][rg] + vbr) * sigm(acc[3][mt][rg] + vbrg);
                float ov = sigm(acc[4][mt][rg] + vbog);
                ogb[(pl + rg) * 128 + h] = __float2half(ov);   // f16 in LDS
            }
            uint2 lp2, rp2;
            lp2.x = cvtpk(lvf[0], lvf[1]); lp2.y = cvtpk(lvf[2], lvf[3]);
            rp2.x = cvtpk(rvf[0], rvf[1]); rp2.y = cvtpk(rvf[2], rvf[3]);
            // fragment-order store: p = p0 + pl + rg
            const int pc = (p0 >> 5) + w;
            const int pq = mt * 2 + (quad >> 1);
            const int pr = (quad & 1) * 4;
            const long off = ((fb + pc) << 9) + qm * 32 + pq * 8 + pr;
            *(uint2*)(lT + off) = lp2;
            *(uint2*)(rT + off) = rp2;
        }
    }
    __syncthreads();

    // ---- og bulk store: contiguous 512B f32 per p-row ----
    {
#pragma unroll
        for (int it = 0; it < 16; ++it) {
            const int prow = it * 8 + w * 2 + (lane >> 5);   // local p row
            const int hq   = (lane & 31) * 4;                // 4-elem h chunk
            const __half2* s2 = (const __half2*)(ogb + prow * 128 + hq);
            float2 f01 = __half22float2(s2[0]);
            float2 f23 = __half22float2(s2[1]);
            float4 o = {f01.x, f01.y, f23.x, f23.y};
            *(float4*)(og + ((long)((b * NN + p0 + prow) * NN + q)) * DD + hq) = o;
        }
    }
}

// ---------------------------------------------------------------------------
// Kernel 3: mix.  Per (b,d): C[i,j] = sum_k right[k,i]*left[k,j].  lT/rT are
// in MFMA-fragment order, so each A/B fragment is ONE dense 1KB run:
//   addr = ((bd*16 + i_tile)*8 + kc)*512 + m*32 + quad*8
// Block tile 128x128, wave tile 64x64.  Output mx bf16 in [b,d,i,j].
// Operands SWAPPED in the MFMA (mfma(b,a)) so the D-tile is transposed:
// lane's 4 acc regs = 4 consecutive j -> uint2 stores via cvt_pk.
// ---------------------------------------------------------------------------
__global__ __launch_bounds__(256)
void k_mix(const u16* __restrict__ lT, const u16* __restrict__ rT,
           u16* __restrict__ mx)
{
    const int tid = threadIdx.x;
    const int bx  = blockIdx.x;
    const int bd  = bx >> 2;               // b*128 + d
    const int it  = (bx >> 1) & 1, jt = bx & 1;
    const int w = tid >> 6, lane = tid & 63, quad = lane >> 4, m = lane & 15;
    const int ib = it * 128 + (w >> 1) * 64;
    const int jb = jt * 128 + (w & 1) * 64;
    const int iqt = it * 8 + (w >> 1) * 4;   // base i-tile (qt) index
    const int jqt = jt * 8 + (w & 1) * 4;    // base j-tile (qt) index
    const int fo = m * 32 + quad * 8;        // lane offset within fragment

    f32x4 acc[4][4];
    const f32x4 zero = {0.f, 0.f, 0.f, 0.f};
#pragma unroll
    for (int a = 0; a < 4; ++a)
#pragma unroll
        for (int c = 0; c < 4; ++c) acc[a][c] = zero;

#pragma unroll 1
    for (int kc = 0; kc < 8; ++kc) {
        short8 afr[4], bfr[4];
#pragma unroll
        for (int tI = 0; tI < 4; ++tI)
            afr[tI] = *(const short8*)(rT + (((long)(bd * 16 + iqt + tI) << 3) + kc) * 512 + fo);
#pragma unroll
        for (int tJ = 0; tJ < 4; ++tJ)
            bfr[tJ] = *(const short8*)(lT + (((long)(bd * 16 + jqt + tJ) << 3) + kc) * 512 + fo);
#pragma unroll
        for (int tI = 0; tI < 4; ++tI)
#pragma unroll
            for (int tJ = 0; tJ < 4; ++tJ)
                acc[tI][tJ] = __builtin_amdgcn_mfma_f32_16x16x32_bf16(bfr[tJ], afr[tI], acc[tI][tJ], 0, 0, 0);
    }

    // D is transposed: col = i = m, row = j = quad*4+rg -> j-contiguous stores
#pragma unroll
    for (int tI = 0; tI < 4; ++tI)
#pragma unroll
        for (int tJ = 0; tJ < 4; ++tJ) {
            const int i = ib + tI * 16 + m;
            const int j = jb + tJ * 16 + quad * 4;
            uint2 vv;
            vv.x = cvtpk(acc[tI][tJ][0], acc[tI][tJ][1]);
            vv.y = cvtpk(acc[tI][tJ][2], acc[tI][tJ][3]);
            *(uint2*)(mx + (long)bd * 65536 + i * 256 + j) = vv;
        }
}

// ---------------------------------------------------------------------------
// Kernel 4: final.  Block = (b, i, j-tile of 64).  Loads mx[b,:,i,j0:j0+64]
// (coalesced per d-row), LN over d per j, * ogate (f32), then y @ w_outT +
// b_out -> f32 out.  og aliases out: each block reads only its own rows
// before overwriting them (disjoint across blocks).
// w_out read in fragment order (coalesced).  Output staged in LDS and
// written as one contiguous 32 KiB block.
// ---------------------------------------------------------------------------
__global__ __launch_bounds__(256)
void k_final(const u16* __restrict__ mx, const float* __restrict__ og,
             const u16* __restrict__ wT5, const float* __restrict__ ong,
             const float* __restrict__ onb, const float* __restrict__ bo_,
             float* __restrict__ out)
{
    // layout: [0,18432)   m1  : uint4 [128][9]  (8 data + 1 pad) bf16
    //         [18432,34816) ys: uint4 [64][16]  bf16 A-frag layout
    //         [34816,35072) mu_s, [35072,35328) rs_s
    //         outs f32 [64 j][128 e] = [0,32768)  -- reuses m1+ys after barrier
    __shared__ __align__(16) unsigned char smem[35328];
    uint4* m1   = (uint4*)smem;
    uint4* ys   = (uint4*)(smem + 18432);
    float* mu_s = (float*)(smem + 34816);
    float* rs_s = (float*)(smem + 35072);
    float* outs = (float*)smem;

    const int tid = threadIdx.x;
    const int bx  = blockIdx.x;
    const int b   = bx >> 10;
    const int i   = (bx >> 2) & 255;
    const int j0  = (bx & 3) * 64;
    const long base = ((long)b * 128) * 65536 + (long)i * 256 + j0;

    {   // load mixed tile: 128 d-rows x 64 j (bf16)
        const int dr = tid >> 3, cc = tid & 7;
#pragma unroll
        for (int pass = 0; pass < 4; ++pass) {
            const int d = pass * 32 + dr;
            m1[d * 9 + cc] = *(const uint4*)(mx + base + (long)d * 65536 + cc * 8);
        }
    }
    __syncthreads();

    if (tid < 128) {   // stats: 2 threads per j
        const int j = tid >> 1, half = tid & 1;
        float s1 = 0.f, s2 = 0.f;
        for (int d = half * 64; d < half * 64 + 64; ++d) {
            float v = b2f(((const u16*)(m1 + d * 9))[j]);
            s1 += v; s2 += v * v;
        }
        s1 += __shfl_xor(s1, 1); s2 += __shfl_xor(s2, 1);
        if (half == 0) {
            const float mu = s1 * (1.f / 128.f);
            mu_s[j] = mu;
            rs_s[j] = rsqrtf(s2 * (1.f / 128.f) - mu * mu + 1e-5f);
        }
    }
    __syncthreads();

    {   // y = (LN(mixed) * ogate) staged bf16 in A-frag layout
        const int j = tid >> 2, c2 = tid & 3;
        const float mu = mu_s[j], rs = rs_s[j];
        const long orow = ((long)((b * NN + i) * NN + j0 + j)) * DD;
#pragma unroll
        for (int s4 = 0; s4 < 4; ++s4) {
            const int ch = c2 * 4 + s4;          // d chunk 0..15
            float4 o0 = *(const float4*)(og + orow + ch * 8);
            float4 o1 = *(const float4*)(og + orow + ch * 8 + 4);
            float4 g0 = *(const float4*)(ong + ch * 8);
            float4 g1 = *(const float4*)(ong + ch * 8 + 4);
            float4 n0 = *(const float4*)(onb + ch * 8);
            float4 n1 = *(const float4*)(onb + ch * 8 + 4);
            float ov[8] = {o0.x,o0.y,o0.z,o0.w,o1.x,o1.y,o1.z,o1.w};
            float gv[8] = {g0.x,g0.y,g0.z,g0.w,g1.x,g1.y,g1.z,g1.w};
            float bv[8] = {n0.x,n0.y,n0.z,n0.w,n1.x,n1.y,n1.z,n1.w};
            float yv[8];
#pragma unroll
            for (int jj = 0; jj < 8; ++jj) {
                const int d = ch * 8 + jj;
                const float v = b2f(((const u16*)(m1 + d * 9))[j]);
                yv[jj] = ((v - mu) * rs * gv[jj] + bv[jj]) * ov[jj];
            }
            uint4 pkv;
            pkv.x = cvtpk(yv[0], yv[1]);
            pkv.y = cvtpk(yv[2], yv[3]);
            pkv.z = cvtpk(yv[4], yv[5]);
            pkv.w = cvtpk(yv[6], yv[7]);
            ys[j * 16 + (ch ^ (j & 15))] = pkv;
        }
    }
    __syncthreads();

    // GEMM: 64 j-rows x 128 e, K = 128.  wave w -> m-tile w.
    const int w = tid >> 6, lane = tid & 63, quad = lane >> 4, m = lane & 15;
    short8 afr[4];
#pragma unroll
    for (int s = 0; s < 4; ++s)
        afr[s] = *(const short8*)(ys + (w * 16 + m) * 16 + ((s * 4 + quad) ^ m));
    __syncthreads();   // ys consumed -> safe to reuse LDS as outs

#pragma unroll 1
    for (int et = 0; et < 8; ++et) {
        f32x4 acc = {0.f, 0.f, 0.f, 0.f};
#pragma unroll
        for (int s = 0; s < 4; ++s) {
            // fragment-ordered w_out: coalesced lane*16B loads
            short8 bfr = *(const short8*)(wT5 + (((et << 2) + s) << 9) + (lane << 3));
            acc = __builtin_amdgcn_mfma_f32_16x16x32_bf16(afr[s], bfr, acc, 0, 0, 0);
        }
        const int e = et * 16 + m;
        const float bo = bo_[e];
#pragma unroll
        for (int rg = 0; rg < 4; ++rg) {
            const int jl = w * 16 + quad * 4 + rg;
            outs[jl * 128 + e] = acc[rg] + bo;
        }
    }
    __syncthreads();

    {   // bulk store: 64 rows x 512B, fully contiguous 32 KiB per block
#pragma unroll
        for (int it2 = 0; it2 < 8; ++it2) {
            const int jl = it2 * 8 + w * 2 + (lane >> 5);
            const int e4 = (lane & 31) * 4;
            float4 o = *(const float4*)(outs + jl * 128 + e4);
            *(float4*)(out + ((long)((b * NN + i) * NN + j0 + jl)) * DD + e4) = o;
        }
    }
}

// ---------------------------------------------------------------------------
extern "C" void kernel_launch(void* const* d_in, const int* in_sizes, int n_in,
                              void* d_out, int out_size, void* d_ws, size_t ws_size,
                              hipStream_t stream) {
    const float* x   = (const float*)d_in[0];
    const float* ng  = (const float*)d_in[1];
    const float* nb  = (const float*)d_in[2];
    const float* wl  = (const float*)d_in[3];
    const float* bl  = (const float*)d_in[4];
    const float* wr  = (const float*)d_in[5];
    const float* br  = (const float*)d_in[6];
    const float* wlg = (const float*)d_in[7];
    const float* blg = (const float*)d_in[8];
    const float* wrg = (const float*)d_in[9];
    const float* brg = (const float*)d_in[10];
    const float* wog = (const float*)d_in[11];
    const float* bog = (const float*)d_in[12];
    const float* ong = (const float*)d_in[13];
    const float* onb = (const float*)d_in[14];
    const float* wo  = (const float*)d_in[15];
    const float* bo  = (const float*)d_in[16];

    u16* ws = (u16*)d_ws;
    const long BIG = 33554432;          // 4*128*256*256 elements
    // Workspace: lT, rT, mx (bf16, 3 x 64 MiB) + 192 KiB bf16 weights.
    // og (f32) aliases d_out: k_lngemm writes it, k_final reads each block's
    // own rows before overwriting them with the f32 output.
    const size_t need = (size_t)(3 * BIG + 6 * 16384) * sizeof(u16);
    if (ws_size < need) return;  // clean failure instead of OOB fault

    u16* lT = ws;                        // bf16, fragment order (see k_lngemm)
    u16* rT = lT + BIG;                  // bf16, fragment order
    u16* mx = rT + BIG;                  // bf16 [b,d,i,j]
    u16* wT = mx + BIG;                  // bf16, 6 mats in MFMA fragment order
    float* og = (float*)d_out;           // f32 [(b,i,j)][h]  (aliases d_out)

    k_tw<<<48, 256, 0, stream>>>(wl, wlg, wr, wrg, wog, wo, wT);
    k_lngemm<<<2048, 256, 0, stream>>>(x, ng, nb, wT, bl, blg, br, brg, bog, lT, rT, og);
    k_mix<<<2048, 256, 0, stream>>>(lT, rT, mx);
    k_final<<<4096, 256, 0, stream>>>(mx, og, wT + 5 * 16384, ong, onb, bo, (float*)d_out);
}

// Round 4
// 473.665 us; speedup vs baseline: 1.3644x; 1.0962x over previous
//
#include <hip/hip_runtime.h>
#include <hip/hip_fp16.h>

typedef unsigned short u16;
typedef unsigned int   u32;
typedef __attribute__((ext_vector_type(8))) short short8;
typedef __attribute__((ext_vector_type(4))) float f32x4;

#define NN 256
#define DD 128

__device__ __forceinline__ u16 f2b(float f) {
    union { float f; u32 i; } v; v.f = f;
    u32 x = v.i;
    return (u16)((x + 0x7FFFu + ((x >> 16) & 1u)) >> 16);  // RTN-even
}
__device__ __forceinline__ float b2f(u16 u) {
    union { u32 i; float f; } v; v.i = ((u32)u) << 16; return v.f;
}
// HW packed f32->bf16 (RNE), 1 instr for 2 values: lo in [15:0], hi in [31:16]
__device__ __forceinline__ u32 cvtpk(float lo, float hi) {
    u32 r;
    asm("v_cvt_pk_bf16_f32 %0, %1, %2" : "=v"(r) : "v"(lo), "v"(hi));
    return r;
}
__device__ __forceinline__ float sigm(float z) { return 1.f / (1.f + __expf(-z)); }

// ---------------------------------------------------------------------------
// Kernel 1: repack 6 f32 weight matrices [d][h] into bf16 MFMA B-fragment
// order: frag[(mat*8+nt)*4+s][lane][8] where lane=(quad<<4)|m holds
// w[d = s*32+quad*8 .. +8][h = nt*16+m].
// order: 0=w_left 1=w_lgate 2=w_right 3=w_rgate 4=w_ogate 5=w_out
// ---------------------------------------------------------------------------
__global__ void k_tw(const float* w0, const float* w1, const float* w2,
                     const float* w3, const float* w4, const float* w5,
                     u16* __restrict__ out) {
    int t = blockIdx.x * 256 + threadIdx.x;   // 12288 threads, 8 outputs each
    int mat = t >> 11, idx = t & 2047;        // idx = (nt*4+s)*64 + lane
    int lane = idx & 63;
    int s    = (idx >> 6) & 3;
    int nt   = idx >> 8;
    int m = lane & 15, quad = lane >> 4;
    int h  = nt * 16 + m;
    int d0 = s * 32 + quad * 8;
    const float* src = (mat == 0) ? w0 : (mat == 1) ? w1 : (mat == 2) ? w2
                      : (mat == 3) ? w3 : (mat == 4) ? w4 : w5;
    u16 vals[8];
#pragma unroll
    for (int j = 0; j < 8; ++j) vals[j] = f2b(src[(d0 + j) * 128 + h]);
    *(uint4*)(out + (t << 3)) = *(uint4*)vals;   // t*8 = mat*16384 + idx*8
}

// ---------------------------------------------------------------------------
// Kernel 2: LayerNorm + 5 GEMMs + gating.
// Block = (b, q, ptile): 128 rows (b, p0..p0+127, q).
// LN loads: 32 lanes/row x contiguous float4 (2-seg instrs, was 64-seg).
// left/right stored bf16 in MFMA-fragment order (k_mix loads dense).
// ogate: f16 in LDS, bulk-copied RAW into the first 256B of each 512B
// d_out row slot (block-local aliasing; halves og traffic).
// ---------------------------------------------------------------------------
__global__ __launch_bounds__(256, 4)
void k_lngemm(const float* __restrict__ x,
              const float* __restrict__ ng,  const float* __restrict__ nb,
              const u16*   __restrict__ wT,
              const float* __restrict__ bL,  const float* __restrict__ bLG,
              const float* __restrict__ bR,  const float* __restrict__ bRG,
              const float* __restrict__ bOG,
              u16* __restrict__ lT, u16* __restrict__ rT, u16* __restrict__ ogu)
{
    // 32 KiB union: phase 1 = xn bf16 tile, phase 2 = ogate f16 buffer.
    __shared__ uint4 smem4[128 * 16];
    uint4*  xs  = smem4;                 // [row][chunk ^ (row&15)] 16B units
    __half* ogb = (__half*)smem4;        // [p_local 128][h 128] f16 (32768 B)

    const int tid = threadIdx.x;
    const int bx  = blockIdx.x;
    const int b   = bx >> 9;
    const int q   = (bx >> 1) & 255;
    const int p0  = (bx & 1) * 128;

    // ---- LN phase: 32 lanes per row (contiguous 512B), 8 rows per pass ----
    {
        const int rr = tid >> 5;   // row-within-pass 0..7
        const int c  = tid & 31;   // float4 chunk 0..31
        float4 gv = *(const float4*)(ng + c * 4);
        float4 bv = *(const float4*)(nb + c * 4);
#pragma unroll
        for (int pass = 0; pass < 16; ++pass) {
            const int r = pass * 8 + rr;                  // local row 0..127
            const long gRow = (long)((b * NN + p0 + r) * NN + q);
            float4 xv = *(const float4*)(x + gRow * DD + c * 4);
            float s1 = xv.x + xv.y + xv.z + xv.w;
            float s2 = xv.x*xv.x + xv.y*xv.y + xv.z*xv.z + xv.w*xv.w;
#pragma unroll
            for (int off = 1; off < 32; off <<= 1) {
                s1 += __shfl_xor(s1, off);
                s2 += __shfl_xor(s2, off);
            }
            const float mu = s1 * (1.f / 128.f);
            const float rs = rsqrtf(s2 * (1.f / 128.f) - mu * mu + 1e-5f);
            uint2 pk;
            pk.x = cvtpk((xv.x-mu)*rs*gv.x+bv.x, (xv.y-mu)*rs*gv.y+bv.y);
            pk.y = cvtpk((xv.z-mu)*rs*gv.z+bv.z, (xv.w-mu)*rs*gv.w+bv.w);
            // 16B chunk ch = c>>1 (half c&1), xor-swizzled like before
            ((uint2*)xs)[(r * 16 + ((c >> 1) ^ (r & 15))) * 2 + (c & 1)] = pk;
        }
    }
    __syncthreads();

    // ---- GEMM phase: wave w owns rows w*32..w*32+31 (2 m-tiles) ----
    const int w = tid >> 6, lane = tid & 63, quad = lane >> 4, m = lane & 15;

    short8 af[2][4];
#pragma unroll
    for (int mt = 0; mt < 2; ++mt)
#pragma unroll
        for (int s = 0; s < 4; ++s) {
            const int row = w * 32 + mt * 16 + m;
            af[mt][s] = *(const short8*)(xs + row * 16 + ((s * 4 + quad) ^ m));
        }
    __syncthreads();   // xs consumed by all waves -> safe to reuse as ogb

    const int qt = q >> 4, qm = q & 15;

#pragma unroll 2
    for (int nt = 0; nt < 8; ++nt) {
        const int h = nt * 16 + m;
        f32x4 acc[5][2];
        const f32x4 zero = {0.f, 0.f, 0.f, 0.f};
#pragma unroll
        for (int g5 = 0; g5 < 5; ++g5) { acc[g5][0] = zero; acc[g5][1] = zero; }

#pragma unroll
        for (int g5 = 0; g5 < 5; ++g5) {
            // fragment-ordered weights: coalesced lane*16B loads
            const u16* wfb = wT + ((((g5 << 3) + nt) << 2) << 9) + (lane << 3);
#pragma unroll
            for (int s = 0; s < 4; ++s) {
                short8 bf = *(const short8*)(wfb + (s << 9));
                acc[g5][0] = __builtin_amdgcn_mfma_f32_16x16x32_bf16(af[0][s], bf, acc[g5][0], 0, 0, 0);
                acc[g5][1] = __builtin_amdgcn_mfma_f32_16x16x32_bf16(af[1][s], bf, acc[g5][1], 0, 0, 0);
            }
        }
        const float vbl  = bL[h],  vblg = bLG[h];
        const float vbr  = bR[h],  vbrg = bRG[h];
        const float vbog = bOG[h];
        const long fb = ((long)(b * 128 + h) * 16 + qt) * 8;
#pragma unroll
        for (int mt = 0; mt < 2; ++mt) {
            const int pl = w * 32 + mt * 16 + quad * 4;   // local p base (4 consecutive)
            float lvf[4], rvf[4];
#pragma unroll
            for (int rg = 0; rg < 4; ++rg) {
                lvf[rg] = (acc[0][mt][rg] + vbl) * sigm(acc[1][mt][rg] + vblg);
                rvf[rg] = (acc[2][mt][rg] + vbr) * sigm(acc[3][mt][rg] + vbrg);
                float ov = sigm(acc[4][mt][rg] + vbog);
                ogb[(pl + rg) * 128 + h] = __float2half(ov);   // f16 in LDS
            }
            uint2 lp2, rp2;
            lp2.x = cvtpk(lvf[0], lvf[1]); lp2.y = cvtpk(lvf[2], lvf[3]);
            rp2.x = cvtpk(rvf[0], rvf[1]); rp2.y = cvtpk(rvf[2], rvf[3]);
            // fragment-order store: p = p0 + pl + rg
            const int pc = (p0 >> 5) + w;
            const int pq = mt * 2 + (quad >> 1);
            const int pr = (quad & 1) * 4;
            const long off = ((fb + pc) << 9) + qm * 32 + pq * 8 + pr;
            *(uint2*)(lT + off) = lp2;
            *(uint2*)(rT + off) = rp2;
        }
    }
    __syncthreads();

    // ---- og bulk store: raw f16 copy, 256B contiguous per p-row ----
    {
#pragma unroll
        for (int it = 0; it < 16; ++it) {
            const int prow = it * 8 + w * 2 + (lane >> 5);   // local p row
            const int hq   = (lane & 31) * 4;                // 4-elem h chunk
            uint2 o = *(const uint2*)(ogb + prow * 128 + hq);
            // og row slot = first 256B of the 512B out-row slot
            *(uint2*)(ogu + ((long)((b * NN + p0 + prow) * NN + q)) * 256 + hq) = o;
        }
    }
}

// ---------------------------------------------------------------------------
// Kernel 3: mix.  Per (b,d): C[i,j] = sum_k right[k,i]*left[k,j].  lT/rT in
// MFMA-fragment order -> dense 1KB fragment loads.  Output staged in LDS
// (XOR-swizzled) and bulk-stored as 256B row runs (was 16-seg scatter).
// ---------------------------------------------------------------------------
__global__ __launch_bounds__(256)
void k_mix(const u16* __restrict__ lT, const u16* __restrict__ rT,
           u16* __restrict__ mx)
{
    __shared__ u16 Cs[128 * 128];   // 32 KiB C-tile
    const int tid = threadIdx.x;
    const int bx  = blockIdx.x;
    const int bd  = bx >> 2;               // b*128 + d
    const int it  = (bx >> 1) & 1, jt = bx & 1;
    const int w = tid >> 6, lane = tid & 63, quad = lane >> 4, m = lane & 15;
    const int iwl = (w >> 1) * 64;           // wave tile origin within Cs
    const int jwl = (w & 1) * 64;
    const int iqt = it * 8 + (w >> 1) * 4;   // base i-tile (qt) index
    const int jqt = jt * 8 + (w & 1) * 4;    // base j-tile (qt) index
    const int fo = m * 32 + quad * 8;        // lane offset within fragment

    f32x4 acc[4][4];
    const f32x4 zero = {0.f, 0.f, 0.f, 0.f};
#pragma unroll
    for (int a = 0; a < 4; ++a)
#pragma unroll
        for (int c = 0; c < 4; ++c) acc[a][c] = zero;

#pragma unroll 1
    for (int kc = 0; kc < 8; ++kc) {
        short8 afr[4], bfr[4];
#pragma unroll
        for (int tI = 0; tI < 4; ++tI)
            afr[tI] = *(const short8*)(rT + (((long)(bd * 16 + iqt + tI) << 3) + kc) * 512 + fo);
#pragma unroll
        for (int tJ = 0; tJ < 4; ++tJ)
            bfr[tJ] = *(const short8*)(lT + (((long)(bd * 16 + jqt + tJ) << 3) + kc) * 512 + fo);
#pragma unroll
        for (int tI = 0; tI < 4; ++tI)
#pragma unroll
            for (int tJ = 0; tJ < 4; ++tJ)
                acc[tI][tJ] = __builtin_amdgcn_mfma_f32_16x16x32_bf16(bfr[tJ], afr[tI], acc[tI][tJ], 0, 0, 0);
    }

    // D transposed: col = i = m, row = j = quad*4+rg -> uint2 into LDS
#pragma unroll
    for (int tI = 0; tI < 4; ++tI)
#pragma unroll
        for (int tJ = 0; tJ < 4; ++tJ) {
            const int iL = iwl + tI * 16 + m;
            const int jL = jwl + tJ * 16 + quad * 4;
            uint2 vv;
            vv.x = cvtpk(acc[tI][tJ][0], acc[tI][tJ][1]);
            vv.y = cvtpk(acc[tI][tJ][2], acc[tI][tJ][3]);
            *(uint2*)(Cs + iL * 128 + (jL ^ ((iL & 7) << 3))) = vv;
        }
    __syncthreads();

    // bulk store: 128 rows x 256B contiguous (2-seg instrs)
    {
        const int ir = tid >> 5, cc = tid & 31;
        const int ib0 = it * 128, jb0 = jt * 128;
#pragma unroll
        for (int pass = 0; pass < 16; ++pass) {
            const int iL = pass * 8 + ir;
            uint2 v = *(const uint2*)(Cs + iL * 128 + ((cc * 4) ^ ((iL & 7) << 3)));
            *(uint2*)(mx + (long)bd * 65536 + (ib0 + iL) * 256 + jb0 + cc * 4) = v;
        }
    }
}

// ---------------------------------------------------------------------------
// Kernel 4: final.  Block = (b, i, j-tile of 64).  Loads mx[b,:,i,j0:j0+64],
// LN over d per j, * ogate (f16, packed in d_out row slots — each block reads
// only its own rows before overwriting them), then y @ w_outT + b_out.
// og prefetched to registers (2-seg row loads).  Output via LDS bulk store.
// ---------------------------------------------------------------------------
__global__ __launch_bounds__(256)
void k_final(const u16* __restrict__ mx, const u16* __restrict__ ogu,
             const u16* __restrict__ wT5, const float* __restrict__ ong,
             const float* __restrict__ onb, const float* __restrict__ bo_,
             float* __restrict__ out)
{
    // layout: [0,18432)   m1  : uint4 [128][9]  (8 data + 1 pad) bf16
    //         [18432,34816) ys: uint4 [64][16]  bf16 A-frag layout
    //         [34816,35072) mu_s, [35072,35328) rs_s
    //         outs f32 [64 j][128 e] = [0,32768)  -- reuses m1+ys after barrier
    __shared__ __align__(16) unsigned char smem[35328];
    uint4* m1   = (uint4*)smem;
    uint4* ys   = (uint4*)(smem + 18432);
    float* mu_s = (float*)(smem + 34816);
    float* rs_s = (float*)(smem + 35072);
    float* outs = (float*)smem;

    const int tid = threadIdx.x;
    const int bx  = blockIdx.x;
    const int b   = bx >> 10;
    const int i   = (bx >> 2) & 255;
    const int j0  = (bx & 3) * 64;
    const long base = ((long)b * 128) * 65536 + (long)i * 256 + j0;

    // ---- og prefetch: 8 x uint2, row-contiguous (2-seg instrs) ----
    uint2 ogp[8];
    {
        const int rr = tid >> 5, c = tid & 31;
#pragma unroll
        for (int pass = 0; pass < 8; ++pass) {
            const long r = (long)((b * NN + i) * NN + j0 + pass * 8 + rr);
            ogp[pass] = *(const uint2*)(ogu + r * 256 + c * 4);
        }
    }

    {   // load mixed tile: 128 d-rows x 64 j (bf16)
        const int dr = tid >> 3, cc = tid & 7;
#pragma unroll
        for (int pass = 0; pass < 4; ++pass) {
            const int d = pass * 32 + dr;
            m1[d * 9 + cc] = *(const uint4*)(mx + base + (long)d * 65536 + cc * 8);
        }
    }
    __syncthreads();

    if (tid < 128) {   // stats: 2 threads per j
        const int j = tid >> 1, half = tid & 1;
        float s1 = 0.f, s2 = 0.f;
        for (int d = half * 64; d < half * 64 + 64; ++d) {
            float v = b2f(((const u16*)(m1 + d * 9))[j]);
            s1 += v; s2 += v * v;
        }
        s1 += __shfl_xor(s1, 1); s2 += __shfl_xor(s2, 1);
        if (half == 0) {
            const float mu = s1 * (1.f / 128.f);
            mu_s[j] = mu;
            rs_s[j] = rsqrtf(s2 * (1.f / 128.f) - mu * mu + 1e-5f);
        }
    }
    __syncthreads();

    {   // y = (LN(mixed) * ogate) staged bf16 in A-frag layout
        const int rr = tid >> 5, c = tid & 31;
        float4 gv4 = *(const float4*)(ong + c * 4);
        float4 bv4 = *(const float4*)(onb + c * 4);
        const float gvv[4] = {gv4.x, gv4.y, gv4.z, gv4.w};
        const float bvv[4] = {bv4.x, bv4.y, bv4.z, bv4.w};
#pragma unroll
        for (int pass = 0; pass < 8; ++pass) {
            const int j = pass * 8 + rr;
            const float mu = mu_s[j], rs = rs_s[j];
            const __half* oh = (const __half*)&ogp[pass];
            float yv[4];
#pragma unroll
            for (int k = 0; k < 4; ++k) {
                const int d = c * 4 + k;
                const float v = b2f(((const u16*)m1)[d * 72 + j]);
                yv[k] = ((v - mu) * rs * gvv[k] + bvv[k]) * __half2float(oh[k]);
            }
            uint2 pk;
            pk.x = cvtpk(yv[0], yv[1]);
            pk.y = cvtpk(yv[2], yv[3]);
            ((uint2*)ys)[(j * 16 + ((c >> 1) ^ (j & 15))) * 2 + (c & 1)] = pk;
        }
    }
    __syncthreads();

    // GEMM: 64 j-rows x 128 e, K = 128.  wave w -> m-tile w.
    const int w = tid >> 6, lane = tid & 63, quad = lane >> 4, m = lane & 15;
    short8 afr[4];
#pragma unroll
    for (int s = 0; s < 4; ++s)
        afr[s] = *(const short8*)(ys + (w * 16 + m) * 16 + ((s * 4 + quad) ^ m));
    __syncthreads();   // ys consumed -> safe to reuse LDS as outs

#pragma unroll 1
    for (int et = 0; et < 8; ++et) {
        f32x4 acc = {0.f, 0.f, 0.f, 0.f};
#pragma unroll
        for (int s = 0; s < 4; ++s) {
            // fragment-ordered w_out: coalesced lane*16B loads
            short8 bfr = *(const short8*)(wT5 + (((et << 2) + s) << 9) + (lane << 3));
            acc = __builtin_amdgcn_mfma_f32_16x16x32_bf16(afr[s], bfr, acc, 0, 0, 0);
        }
        const int e = et * 16 + m;
        const float bo = bo_[e];
#pragma unroll
        for (int rg = 0; rg < 4; ++rg) {
            const int jl = w * 16 + quad * 4 + rg;
            outs[jl * 128 + e] = acc[rg] + bo;
        }
    }
    __syncthreads();

    {   // bulk store: 64 rows x 512B, fully contiguous 32 KiB per block
#pragma unroll
        for (int it2 = 0; it2 < 8; ++it2) {
            const int jl = it2 * 8 + w * 2 + (lane >> 5);
            const int e4 = (lane & 31) * 4;
            float4 o = *(const float4*)(outs + jl * 128 + e4);
            *(float4*)(out + ((long)((b * NN + i) * NN + j0 + jl)) * DD + e4) = o;
        }
    }
}

// ---------------------------------------------------------------------------
extern "C" void kernel_launch(void* const* d_in, const int* in_sizes, int n_in,
                              void* d_out, int out_size, void* d_ws, size_t ws_size,
                              hipStream_t stream) {
    const float* x   = (const float*)d_in[0];
    const float* ng  = (const float*)d_in[1];
    const float* nb  = (const float*)d_in[2];
    const float* wl  = (const float*)d_in[3];
    const float* bl  = (const float*)d_in[4];
    const float* wr  = (const float*)d_in[5];
    const float* br  = (const float*)d_in[6];
    const float* wlg = (const float*)d_in[7];
    const float* blg = (const float*)d_in[8];
    const float* wrg = (const float*)d_in[9];
    const float* brg = (const float*)d_in[10];
    const float* wog = (const float*)d_in[11];
    const float* bog = (const float*)d_in[12];
    const float* ong = (const float*)d_in[13];
    const float* onb = (const float*)d_in[14];
    const float* wo  = (const float*)d_in[15];
    const float* bo  = (const float*)d_in[16];

    u16* ws = (u16*)d_ws;
    const long BIG = 33554432;          // 4*128*256*256 elements
    // Workspace: lT, rT, mx (bf16, 3 x 64 MiB) + 192 KiB bf16 weights.
    // og (f16) aliases d_out: packed in the first 256B of each 512B out-row
    // slot; k_final reads only its own rows before overwriting them.
    const size_t need = (size_t)(3 * BIG + 6 * 16384) * sizeof(u16);
    if (ws_size < need) return;  // clean failure instead of OOB fault

    u16* lT = ws;                        // bf16, fragment order (see k_lngemm)
    u16* rT = lT + BIG;                  // bf16, fragment order
    u16* mx = rT + BIG;                  // bf16 [b,d,i,j]
    u16* wT = mx + BIG;                  // bf16, 6 mats in MFMA fragment order
    u16* og = (u16*)d_out;               // f16, row-slot packed (aliases d_out)

    k_tw<<<48, 256, 0, stream>>>(wl, wlg, wr, wrg, wog, wo, wT);
    k_lngemm<<<2048, 256, 0, stream>>>(x, ng, nb, wT, bl, blg, br, brg, bog, lT, rT, og);
    k_mix<<<2048, 256, 0, stream>>>(lT, rT, mx);
    k_final<<<4096, 256, 0, stream>>>(mx, og, wT + 5 * 16384, ong, onb, bo, (float*)d_out);
}